// Round 9
// baseline (682.618 us; speedup 1.0000x reference)
//
#include <hip/hip_runtime.h>

#define N_ROWS 65536
#define C_CLUST 512
#define D_DIM 256

// ---- workspace layout (float-index units) ----
#define WS_DICTT   0          // dict bf16 hi (131072 ushort) + lo (131072 ushort)
#define WS_DSQ     131072     // 512
#define WS_XSQ     131584     // 65536
#define WS_CS      197120     // 512
#define WS_DCY     197632     // 512
#define WS_ISUM    198144     // 512*256 = 131072
#define WS_COUNTS  329216     // 512 uint
#define WS_OFFSETS 329728     // 513 uint
#define WS_FILL    330752     // 512 uint
#define WS_ROWLIST 331264     // 262144 uint; FIRST 131072 floats double as
                              // dictT_f32 [256][512] between prep_dict and scatter_k

// ---- output layout (float-index units) ----
#define OUT_GEMB 0
#define OUT_TOPK 16777216
#define OUT_DICT 17039360
#define OUT_CSS  17170432
#define OUT_CV   17170944
#define OUT_CNUM 17302016

#define RPB 128   // rowlist entries per block in cluster_sum2_k

typedef __attribute__((ext_vector_type(8))) short short8;
typedef __attribute__((ext_vector_type(16))) float f32x16;

__device__ __forceinline__ unsigned short f2bf(float v) {
    union { float f; unsigned u; } c; c.f = v;
    unsigned r = c.u + 0x7FFFu + ((c.u >> 16) & 1u);
    return (unsigned short)(r >> 16);
}
__device__ __forceinline__ float bf2f(unsigned short h) {
    union { float f; unsigned u; } c; c.u = ((unsigned)h) << 16;
    return c.f;
}

// ---------- K-zero: zero counters + isum ----------
__global__ void zero_k(unsigned* counts, unsigned* fill, float* isum) {
    int t = blockIdx.x * blockDim.x + threadIdx.x;
    if (t < 512) { counts[t] = 0u; fill[t] = 0u; }
    if (t < C_CLUST * D_DIM) isum[t] = 0.f;
}

// ---------- K0: dict -> bf16 hi/lo split + fp32 transpose + ||d||^2 ----------
__global__ void prep_dict(const float* __restrict__ dic, float* __restrict__ ws) {
    int c = blockIdx.x, k = threadIdx.x;
    float v = dic[c * D_DIM + k];
    unsigned short* dhi = (unsigned short*)(ws + WS_DICTT);
    unsigned short* dlo = dhi + 131072;
    unsigned short hb = f2bf(v);
    dhi[c * D_DIM + k] = hb;
    dlo[c * D_DIM + k] = f2bf(__fsub_rn(v, bf2f(hb)));
    ws[WS_ROWLIST + k * C_CLUST + c] = v;   // dictT_f32 (rowlist region, pre-scatter)
    __shared__ float red[256];
    red[k] = v * v;
    __syncthreads();
    for (int s = 128; s > 0; s >>= 1) {
        if (k < s) red[k] += red[k + s];
        __syncthreads();
    }
    if (k == 0) ws[WS_DSQ + c] = red[0];
}

// ---------- K0b: ||x||^2 per row (reference tree order) ----------
__global__ void row_sq(const float* __restrict__ x, float* __restrict__ ws) {
    int row = blockIdx.x, k = threadIdx.x;
    float v = x[row * D_DIM + k];
    __shared__ float red[256];
    red[k] = v * v;
    __syncthreads();
    for (int s = 128; s > 0; s >>= 1) {
        if (k < s) red[k] += red[k + s];
        __syncthreads();
    }
    if (k == 0) ws[WS_XSQ + row] = red[0];
}

// ---------- K1: split-bf16 MFMA candidate generation (top-8 per lane-half,
// 16 candidates per row, exact u64 keys) — UNCHANGED ----------
__global__ __launch_bounds__(256, 2) void stage1_cand(
    const float* __restrict__ x, const float* __restrict__ ws,
    float* __restrict__ cand_out)
{
    __shared__ unsigned short hlds[32 * 264];
    __shared__ unsigned short llds[32 * 264];
    __shared__ float dsq_s[512];

    const int tid = threadIdx.x;
    const int lane = tid & 63;
    const int w = tid >> 6;
    const int kg = lane >> 5;              // k-half group: 0 or 1
    const int cl_lane = lane & 31;
    const int row = blockIdx.x * 128 + w * 32 + cl_lane;

    const unsigned short* dhi = (const unsigned short*)(ws + WS_DICTT);
    const unsigned short* dlo = dhi + 131072;

    for (int i = tid; i < 512; i += 256) dsq_s[i] = ws[WS_DSQ + i];

    short8 bhi[16], blo[16];
    #pragma unroll
    for (int s = 0; s < 16; ++s) {
        const float* px = &x[(size_t)row * D_DIM + s * 16 + kg * 8];
        float4 u0 = *reinterpret_cast<const float4*>(px);
        float4 u1 = *reinterpret_cast<const float4*>(px + 4);
        float vv[8] = {u0.x, u0.y, u0.z, u0.w, u1.x, u1.y, u1.z, u1.w};
        short8 h, l;
        #pragma unroll
        for (int e = 0; e < 8; ++e) {
            unsigned short hb = f2bf(vv[e]);
            unsigned short lb = f2bf(__fsub_rn(vv[e], bf2f(hb)));
            h[e] = (short)hb; l[e] = (short)lb;
        }
        bhi[s] = h; blo[s] = l;
    }

    unsigned long long kk[8];
    #pragma unroll
    for (int q = 0; q < 8; ++q) kk[q] = 0xFFFFFFFFFFFFFFFFULL;

    for (int ct = 0; ct < 16; ++ct) {
        __syncthreads();
        for (int q = tid; q < 1024; q += 256) {
            int c = q >> 5, k8 = (q & 31) * 8;
            *reinterpret_cast<uint4*>(&hlds[c * 264 + k8]) =
                *reinterpret_cast<const uint4*>(&dhi[(ct * 32 + c) * D_DIM + k8]);
            *reinterpret_cast<uint4*>(&llds[c * 264 + k8]) =
                *reinterpret_cast<const uint4*>(&dlo[(ct * 32 + c) * D_DIM + k8]);
        }
        __syncthreads();

        f32x16 ahh, ahl, alh;
        #pragma unroll
        for (int r = 0; r < 16; ++r) { ahh[r] = 0.f; ahl[r] = 0.f; alh[r] = 0.f; }

        #pragma unroll
        for (int s = 0; s < 16; ++s) {
            short8 Ah = *reinterpret_cast<const short8*>(
                &hlds[cl_lane * 264 + s * 16 + kg * 8]);
            short8 Al = *reinterpret_cast<const short8*>(
                &llds[cl_lane * 264 + s * 16 + kg * 8]);
            ahh = __builtin_amdgcn_mfma_f32_32x32x16_bf16(Ah, bhi[s], ahh, 0, 0, 0);
            ahl = __builtin_amdgcn_mfma_f32_32x32x16_bf16(Ah, blo[s], ahl, 0, 0, 0);
            alh = __builtin_amdgcn_mfma_f32_32x32x16_bf16(Al, bhi[s], alh, 0, 0, 0);
        }

        #pragma unroll
        for (int r = 0; r < 16; ++r) {
            int cl = ct * 32 + (r & 3) + 8 * (r >> 2) + 4 * kg;
            float dot = ahh[r] + ahl[r] + alh[r];
            float key = (dsq_s[cl] + 1024.0f) - 2.0f * dot;   // > 0 always
            unsigned long long v =
                ((unsigned long long)__float_as_uint(key) << 32) | (unsigned)cl;
            #pragma unroll
            for (int q = 0; q < 8; ++q) {
                bool lt = v < kk[q];
                unsigned long long mn = lt ? v : kk[q];
                unsigned long long mx = lt ? kk[q] : v;
                kk[q] = mn; v = mx;
            }
        }
    }

    uint4 wv;
    wv.x = (unsigned)(kk[0] & 0xFFFF) | ((unsigned)(kk[1] & 0xFFFF) << 16);
    wv.y = (unsigned)(kk[2] & 0xFFFF) | ((unsigned)(kk[3] & 0xFFFF) << 16);
    wv.z = (unsigned)(kk[4] & 0xFFFF) | ((unsigned)(kk[5] & 0xFFFF) << 16);
    wv.w = (unsigned)(kk[6] & 0xFFFF) | ((unsigned)(kk[7] & 0xFFFF) << 16);
    *reinterpret_cast<uint4*>(&cand_out[(size_t)row * 256 + kg * 4]) = wv;
}

// ---------- K2: exact refine v4 — dict STREAMED, zero scattered loads -------
// Block = 64 rows x 16 cands = 1024 pairs, 256 threads (4 chains each:
// one row, 4 cand slots). 16 k-chunks; per chunk stage dictT_f32[16k][512cl]
// (32 KB, coalesced) + x[64r][16k] into LDS; chains read LDS only.
// fmaf chain k=0..255 strictly sequential — bit-identical to prior rounds.
__global__ __launch_bounds__(256, 4) void refine_k(
    const float* __restrict__ x, const float* __restrict__ ws,
    float* __restrict__ out, unsigned* __restrict__ counts)
{
    __shared__ float dlds[16 * 516];   // [k_local][cluster], stride 516
    __shared__ float xlds[16 * 68];    // [k_local][row_local], stride 68
    __shared__ int   cidx[1024];
    __shared__ float distb[1024];

    const int t = threadIdx.x;
    const int rowBase = blockIdx.x * 64;
    const float* dictT = ws + WS_ROWLIST;   // fp32 [256][512]
    const unsigned short* candp = (const unsigned short*)(out + OUT_GEMB);

    // candidate ids: 64 rows x 16 slots
    #pragma unroll
    for (int i = 0; i < 4; ++i) {
        int q = t + i * 256;
        cidx[q] = (int)candp[(size_t)(rowBase + (q >> 4)) * 512 + (q & 15)];
    }
    __syncthreads();

    const int rl = t >> 2;          // row_local 0..63
    const int sb = (t & 3) * 4;     // slot base
    const int c0 = cidx[rl * 16 + sb + 0];
    const int c1 = cidx[rl * 16 + sb + 1];
    const int c2 = cidx[rl * 16 + sb + 2];
    const int c3 = cidx[rl * 16 + sb + 3];

    // prefetch chunk 0 into registers
    float4 dreg[8];
    float4 xreg;
    #pragma unroll
    for (int i = 0; i < 8; ++i)
        dreg[i] = *reinterpret_cast<const float4*>(&dictT[(size_t)(t + i * 256) * 4]);
    xreg = *reinterpret_cast<const float4*>(
        &x[(size_t)(rowBase + (t >> 2)) * D_DIM + (t & 3) * 4]);

    float a0 = 0.f, a1 = 0.f, a2 = 0.f, a3 = 0.f;

    for (int c = 0; c < 16; ++c) {
        // write staged regs to LDS
        #pragma unroll
        for (int i = 0; i < 8; ++i) {
            int g = t + i * 256;
            *reinterpret_cast<float4*>(&dlds[(g >> 7) * 516 + (g & 127) * 4]) = dreg[i];
        }
        {
            int f4 = t & 3, r = t >> 2;
            xlds[(f4 * 4 + 0) * 68 + r] = xreg.x;
            xlds[(f4 * 4 + 1) * 68 + r] = xreg.y;
            xlds[(f4 * 4 + 2) * 68 + r] = xreg.z;
            xlds[(f4 * 4 + 3) * 68 + r] = xreg.w;
        }
        // issue next chunk's loads (latency hides under barrier + compute)
        if (c < 15) {
            #pragma unroll
            for (int i = 0; i < 8; ++i)
                dreg[i] = *reinterpret_cast<const float4*>(
                    &dictT[(size_t)((c + 1) * 2048 + t + i * 256) * 4]);
            xreg = *reinterpret_cast<const float4*>(
                &x[(size_t)(rowBase + (t >> 2)) * D_DIM + (c + 1) * 16 + (t & 3) * 4]);
        }
        __syncthreads();
        // advance 4 chains by 16 k-steps (k = c*16 + kk, strictly sequential)
        #pragma unroll
        for (int kk = 0; kk < 16; ++kk) {
            float xv = xlds[kk * 68 + rl];
            const float* dr = &dlds[kk * 516];
            a0 = fmaf(xv, dr[c0], a0);
            a1 = fmaf(xv, dr[c1], a1);
            a2 = fmaf(xv, dr[c2], a2);
            a3 = fmaf(xv, dr[c3], a3);
        }
        __syncthreads();
    }

    // epilogue: identical formula
    {
        float xs = ws[WS_XSQ + rowBase + rl];
        distb[rl * 16 + sb + 0] =
            __fsub_rn(__fadd_rn(xs, ws[WS_DSQ + c0]), __fmul_rn(2.0f, a0));
        distb[rl * 16 + sb + 1] =
            __fsub_rn(__fadd_rn(xs, ws[WS_DSQ + c1]), __fmul_rn(2.0f, a1));
        distb[rl * 16 + sb + 2] =
            __fsub_rn(__fadd_rn(xs, ws[WS_DSQ + c2]), __fmul_rn(2.0f, a2));
        distb[rl * 16 + sb + 3] =
            __fsub_rn(__fadd_rn(xs, ws[WS_DSQ + c3]), __fmul_rn(2.0f, a3));
    }
    __syncthreads();

    // exact lexicographic top-4 of the 16 candidates per row
    if (t < 64) {
        float bv0 = 3.4e38f, bv1 = 3.4e38f, bv2 = 3.4e38f, bv3 = 3.4e38f;
        int bi0 = 0x7FFFFFFF, bi1 = 0x7FFFFFFF, bi2 = 0x7FFFFFFF, bi3 = 0x7FFFFFFF;
        for (int s = 0; s < 16; ++s) {
            int p = t * 16 + s;
            float v = distb[p];
            int ci = cidx[p];
            if (v < bv3 || (v == bv3 && ci < bi3)) {
                if (v < bv2 || (v == bv2 && ci < bi2)) {
                    bv3 = bv2; bi3 = bi2;
                    if (v < bv1 || (v == bv1 && ci < bi1)) {
                        bv2 = bv1; bi2 = bi1;
                        if (v < bv0 || (v == bv0 && ci < bi0)) {
                            bv1 = bv0; bi1 = bi0;
                            bv0 = v; bi0 = ci;
                        } else { bv1 = v; bi1 = ci; }
                    } else { bv2 = v; bi2 = ci; }
                } else { bv3 = v; bi3 = ci; }
            }
        }
        int row = rowBase + t;
        out[OUT_TOPK + (size_t)row * 4 + 0] = (float)bi0;
        out[OUT_TOPK + (size_t)row * 4 + 1] = (float)bi1;
        out[OUT_TOPK + (size_t)row * 4 + 2] = (float)bi2;
        out[OUT_TOPK + (size_t)row * 4 + 3] = (float)bi3;
        atomicAdd(&counts[bi0], 1u);
        atomicAdd(&counts[bi1], 1u);
        atomicAdd(&counts[bi2], 1u);
        atomicAdd(&counts[bi3], 1u);
    }
}

// ---------- K2b: group_emb, fully coalesced (4 rows/block, 64 lanes/row) ----
__global__ __launch_bounds__(256, 4) void group_emb_k(
    const float* __restrict__ x, const float* __restrict__ dic,
    const float* __restrict__ topk, float* __restrict__ out)
{
    const int t = threadIdx.x;
    const int row = blockIdx.x * 4 + (t >> 6);
    const int k4 = (t & 63) * 4;
    int i0 = (int)topk[(size_t)row * 4 + 0];
    int i1 = (int)topk[(size_t)row * 4 + 1];
    int i2 = (int)topk[(size_t)row * 4 + 2];
    int i3 = (int)topk[(size_t)row * 4 + 3];
    float4 a = *reinterpret_cast<const float4*>(&dic[(size_t)i0 * D_DIM + k4]);
    float4 b = *reinterpret_cast<const float4*>(&dic[(size_t)i1 * D_DIM + k4]);
    float4 c = *reinterpret_cast<const float4*>(&dic[(size_t)i2 * D_DIM + k4]);
    float4 e = *reinterpret_cast<const float4*>(&dic[(size_t)i3 * D_DIM + k4]);
    float4 xv = *reinterpret_cast<const float4*>(&x[(size_t)row * D_DIM + k4]);
    float4 o;
    float g;
    g = __fmul_rn(__fadd_rn(__fadd_rn(__fadd_rn(a.x, b.x), c.x), e.x), 0.25f);
    o.x = __fadd_rn(__fsub_rn(g, xv.x), xv.x);
    g = __fmul_rn(__fadd_rn(__fadd_rn(__fadd_rn(a.y, b.y), c.y), e.y), 0.25f);
    o.y = __fadd_rn(__fsub_rn(g, xv.y), xv.y);
    g = __fmul_rn(__fadd_rn(__fadd_rn(__fadd_rn(a.z, b.z), c.z), e.z), 0.25f);
    o.z = __fadd_rn(__fsub_rn(g, xv.z), xv.z);
    g = __fmul_rn(__fadd_rn(__fadd_rn(__fadd_rn(a.w, b.w), c.w), e.w), 0.25f);
    o.w = __fadd_rn(__fsub_rn(g, xv.w), xv.w);
    *reinterpret_cast<float4*>(&out[OUT_GEMB + (size_t)row * D_DIM + k4]) = o;
}

// ---------- K3: exclusive prefix sum of counts ----------
__global__ void prefix_k(const unsigned* __restrict__ counts, unsigned* __restrict__ offsets) {
    __shared__ unsigned s[512];
    int t = threadIdx.x;
    unsigned my = counts[t];
    s[t] = my;
    __syncthreads();
    for (int off = 1; off < 512; off <<= 1) {
        unsigned v = (t >= off) ? s[t - off] : 0u;
        __syncthreads();
        s[t] += v;
        __syncthreads();
    }
    offsets[t] = s[t] - my;
    if (t == 511) offsets[512] = s[511];
}

// ---------- K4: scatter rows into cluster buckets (packed (c<<16)|row) ----------
__global__ void scatter_k(const float* __restrict__ topk, const unsigned* __restrict__ offsets,
                          unsigned* __restrict__ fill, unsigned* __restrict__ rowlist) {
    int row = blockIdx.x * 256 + threadIdx.x;
    #pragma unroll
    for (int k = 0; k < 4; ++k) {
        int c = (int)topk[row * 4 + k];
        unsigned p = atomicAdd(&fill[c], 1u);
        rowlist[offsets[c] + p] = ((unsigned)c << 16) | (unsigned)row;
    }
}

// ---------- K5: load-balanced segmented sum (encodings^T @ X) ----------
__global__ __launch_bounds__(256, 8) void cluster_sum2_k(
    const float* __restrict__ x, const unsigned* __restrict__ rowlist,
    float* __restrict__ isum)
{
    const int d = threadIdx.x;
    const int base = blockIdx.x * RPB;
    unsigned e0 = rowlist[base];
    int ccur = (int)(e0 >> 16);
    float acc = 0.f;
    #pragma unroll 4
    for (int j = 0; j < RPB; ++j) {
        unsigned e = rowlist[base + j];
        int c = (int)(e >> 16);
        float v = x[(e & 0xFFFFu) * D_DIM + d];
        if (c != ccur) {
            atomicAdd(&isum[ccur * D_DIM + d], acc);
            acc = 0.f;
            ccur = c;
        }
        acc += v;
    }
    atomicAdd(&isum[ccur * D_DIM + d], acc);
}

// ---------- K6: sequential decay scan + css EMA + laplace ----------
__global__ void ema_scalar_k(const float* __restrict__ css_in, const float* __restrict__ cnum_in,
                             const unsigned* __restrict__ counts,
                             float* __restrict__ ws, float* __restrict__ out) {
    __shared__ float sdecay[512];
    __shared__ float sred[512];
    __shared__ float scn[512];
    __shared__ unsigned smask[512];
    int t = threadIdx.x; // 512 threads
    unsigned cnt = counts[t];
    float size = (float)cnt;
    float mask = (cnt != 0u) ? 1.f : 0.f;
    float cnum_new = __fadd_rn(cnum_in[t], mask);
    scn[t] = cnum_new;
    smask[t] = cnt;
    __syncthreads();
    if (t == 0) {
        float d = 0.99f;
        for (int c = 0; c < 512; ++c) {
            if (smask[c] != 0u && scn[c] <= 10.0f)
                d = __fmul_rn(d, scn[c]) / 10.0f;   // (decay*c)/10, IEEE div
            sdecay[c] = d;
        }
    }
    __syncthreads();
    float d = sdecay[t];
    float css = css_in[t];
    float css_new = (cnt != 0u)
        ? __fadd_rn(__fmul_rn(css, d), __fmul_rn(size, __fsub_rn(1.f, d)))
        : css;
    out[OUT_CSS + t] = css_new;
    out[OUT_CNUM + t] = cnum_new;
    sred[t] = css_new;
    __syncthreads();
    for (int s = 256; s > 0; s >>= 1) {
        if (t < s) sred[t] += sred[t + s];
        __syncthreads();
    }
    float S = sred[0];
    float cs = __fmul_rn(__fdiv_rn(__fadd_rn(css_new, 1e-5f),
                                   __fadd_rn(S, 0.00512f)), S);
    ws[WS_CS + t] = cs;
    ws[WS_DCY + t] = d;
}

// ---------- K7: cluster_value EMA + dictionary normalize ----------
__global__ void final_k(const float* __restrict__ cv_in, const float* __restrict__ ws,
                        const unsigned* __restrict__ counts, float* __restrict__ out) {
    int c = blockIdx.x, d = threadIdx.x;
    float isum = ws[WS_ISUM + c * D_DIM + d];
    float dc = ws[WS_DCY + c];
    float cs = ws[WS_CS + c];
    unsigned cnt = counts[c];
    float cv = cv_in[c * D_DIM + d];
    float cvn = (cnt != 0u)
        ? __fadd_rn(__fmul_rn(cv, dc), __fmul_rn(isum, __fsub_rn(1.f, dc)))
        : cv;
    out[OUT_CV + c * D_DIM + d] = cvn;
    out[OUT_DICT + c * D_DIM + d] = (cnt != 0u) ? __fdiv_rn(cvn, cs) : cvn;
}

extern "C" void kernel_launch(void* const* d_in, const int* in_sizes, int n_in,
                              void* d_out, int out_size, void* d_ws, size_t ws_size,
                              hipStream_t stream) {
    const float* x       = (const float*)d_in[0];
    const float* dic     = (const float*)d_in[1];
    const float* css_in  = (const float*)d_in[2];
    const float* cv_in   = (const float*)d_in[3];
    const float* cnum_in = (const float*)d_in[4];
    float* out = (float*)d_out;
    float* ws  = (float*)d_ws;
    unsigned* counts  = (unsigned*)(ws + WS_COUNTS);
    unsigned* offsets = (unsigned*)(ws + WS_OFFSETS);
    unsigned* fill    = (unsigned*)(ws + WS_FILL);
    unsigned* rowlist = (unsigned*)(ws + WS_ROWLIST);

    zero_k<<<C_CLUST * D_DIM / 256, 256, 0, stream>>>(counts, fill, ws + WS_ISUM);
    prep_dict<<<C_CLUST, 256, 0, stream>>>(dic, ws);
    row_sq<<<N_ROWS, 256, 0, stream>>>(x, ws);

    stage1_cand<<<N_ROWS / 128, 256, 0, stream>>>(x, ws, out + OUT_GEMB);

    refine_k<<<N_ROWS / 64, 256, 0, stream>>>(x, ws, out, counts);
    group_emb_k<<<N_ROWS / 4, 256, 0, stream>>>(x, dic, out + OUT_TOPK, out + OUT_GEMB);

    prefix_k<<<1, 512, 0, stream>>>(counts, offsets);
    scatter_k<<<N_ROWS / 256, 256, 0, stream>>>(out + OUT_TOPK, offsets, fill, rowlist);
    cluster_sum2_k<<<N_ROWS * 4 / RPB, 256, 0, stream>>>(x, rowlist, ws + WS_ISUM);
    ema_scalar_k<<<1, 512, 0, stream>>>(css_in, cnum_in, counts, ws, out);
    final_k<<<C_CLUST, 256, 0, stream>>>(cv_in, ws, counts, out);
}

// Round 10
// 629.143 us; speedup vs baseline: 1.0850x; 1.0850x over previous
//
#include <hip/hip_runtime.h>

#define N_ROWS 65536
#define C_CLUST 512
#define D_DIM 256

// ---- workspace layout (float-index units) ----
#define WS_DICTT   0          // dict bf16 hi (131072 ushort) + lo (131072 ushort)
#define WS_DSQ     131072     // 512
#define WS_XSQ     131584     // 65536
#define WS_CS      197120     // 512
#define WS_DCY     197632     // 512
#define WS_ISUM    198144     // 512*256 = 131072
#define WS_COUNTS  329216     // 512 uint
#define WS_OFFSETS 329728     // 513 uint
#define WS_FILL    330752     // 512 uint
#define WS_ROWLIST 331264     // 262144 uint; FIRST 131072 floats double as
                              // dictT_f32 [256][512] between prep_dict and scatter_k

// ---- output layout (float-index units) ----
#define OUT_GEMB 0
#define OUT_TOPK 16777216
#define OUT_DICT 17039360
#define OUT_CSS  17170432
#define OUT_CV   17170944
#define OUT_CNUM 17302016

#define RPB 128   // rowlist entries per block in cluster_sum2_k

typedef __attribute__((ext_vector_type(8))) short short8;
typedef __attribute__((ext_vector_type(16))) float f32x16;

__device__ __forceinline__ unsigned short f2bf(float v) {
    union { float f; unsigned u; } c; c.f = v;
    unsigned r = c.u + 0x7FFFu + ((c.u >> 16) & 1u);
    return (unsigned short)(r >> 16);
}
__device__ __forceinline__ float bf2f(unsigned short h) {
    union { float f; unsigned u; } c; c.u = ((unsigned)h) << 16;
    return c.f;
}

// ---------- K-zero: zero counters + isum ----------
__global__ void zero_k(unsigned* counts, unsigned* fill, float* isum) {
    int t = blockIdx.x * blockDim.x + threadIdx.x;
    if (t < 512) { counts[t] = 0u; fill[t] = 0u; }
    if (t < C_CLUST * D_DIM) isum[t] = 0.f;
}

// ---------- K0: dict -> bf16 hi/lo split + fp32 transpose + ||d||^2 ----------
__global__ void prep_dict(const float* __restrict__ dic, float* __restrict__ ws) {
    int c = blockIdx.x, k = threadIdx.x;
    float v = dic[c * D_DIM + k];
    unsigned short* dhi = (unsigned short*)(ws + WS_DICTT);
    unsigned short* dlo = dhi + 131072;
    unsigned short hb = f2bf(v);
    dhi[c * D_DIM + k] = hb;
    dlo[c * D_DIM + k] = f2bf(__fsub_rn(v, bf2f(hb)));
    ws[WS_ROWLIST + k * C_CLUST + c] = v;   // dictT_f32 (rowlist region, pre-scatter)
    __shared__ float red[256];
    red[k] = v * v;
    __syncthreads();
    for (int s = 128; s > 0; s >>= 1) {
        if (k < s) red[k] += red[k + s];
        __syncthreads();
    }
    if (k == 0) ws[WS_DSQ + c] = red[0];
}

// ---------- K0b: ||x||^2 per row (reference tree order) ----------
__global__ void row_sq(const float* __restrict__ x, float* __restrict__ ws) {
    int row = blockIdx.x, k = threadIdx.x;
    float v = x[row * D_DIM + k];
    __shared__ float red[256];
    red[k] = v * v;
    __syncthreads();
    for (int s = 128; s > 0; s >>= 1) {
        if (k < s) red[k] += red[k + s];
        __syncthreads();
    }
    if (k == 0) ws[WS_XSQ + row] = red[0];
}

// ---------- K1: split-bf16 MFMA candidate generation (top-8 per lane-half,
// 16 candidates per row, exact u64 keys) — UNCHANGED ----------
__global__ __launch_bounds__(256, 2) void stage1_cand(
    const float* __restrict__ x, const float* __restrict__ ws,
    float* __restrict__ cand_out)
{
    __shared__ unsigned short hlds[32 * 264];
    __shared__ unsigned short llds[32 * 264];
    __shared__ float dsq_s[512];

    const int tid = threadIdx.x;
    const int lane = tid & 63;
    const int w = tid >> 6;
    const int kg = lane >> 5;              // k-half group: 0 or 1
    const int cl_lane = lane & 31;
    const int row = blockIdx.x * 128 + w * 32 + cl_lane;

    const unsigned short* dhi = (const unsigned short*)(ws + WS_DICTT);
    const unsigned short* dlo = dhi + 131072;

    for (int i = tid; i < 512; i += 256) dsq_s[i] = ws[WS_DSQ + i];

    short8 bhi[16], blo[16];
    #pragma unroll
    for (int s = 0; s < 16; ++s) {
        const float* px = &x[(size_t)row * D_DIM + s * 16 + kg * 8];
        float4 u0 = *reinterpret_cast<const float4*>(px);
        float4 u1 = *reinterpret_cast<const float4*>(px + 4);
        float vv[8] = {u0.x, u0.y, u0.z, u0.w, u1.x, u1.y, u1.z, u1.w};
        short8 h, l;
        #pragma unroll
        for (int e = 0; e < 8; ++e) {
            unsigned short hb = f2bf(vv[e]);
            unsigned short lb = f2bf(__fsub_rn(vv[e], bf2f(hb)));
            h[e] = (short)hb; l[e] = (short)lb;
        }
        bhi[s] = h; blo[s] = l;
    }

    unsigned long long kk[8];
    #pragma unroll
    for (int q = 0; q < 8; ++q) kk[q] = 0xFFFFFFFFFFFFFFFFULL;

    for (int ct = 0; ct < 16; ++ct) {
        __syncthreads();
        for (int q = tid; q < 1024; q += 256) {
            int c = q >> 5, k8 = (q & 31) * 8;
            *reinterpret_cast<uint4*>(&hlds[c * 264 + k8]) =
                *reinterpret_cast<const uint4*>(&dhi[(ct * 32 + c) * D_DIM + k8]);
            *reinterpret_cast<uint4*>(&llds[c * 264 + k8]) =
                *reinterpret_cast<const uint4*>(&dlo[(ct * 32 + c) * D_DIM + k8]);
        }
        __syncthreads();

        f32x16 ahh, ahl, alh;
        #pragma unroll
        for (int r = 0; r < 16; ++r) { ahh[r] = 0.f; ahl[r] = 0.f; alh[r] = 0.f; }

        #pragma unroll
        for (int s = 0; s < 16; ++s) {
            short8 Ah = *reinterpret_cast<const short8*>(
                &hlds[cl_lane * 264 + s * 16 + kg * 8]);
            short8 Al = *reinterpret_cast<const short8*>(
                &llds[cl_lane * 264 + s * 16 + kg * 8]);
            ahh = __builtin_amdgcn_mfma_f32_32x32x16_bf16(Ah, bhi[s], ahh, 0, 0, 0);
            ahl = __builtin_amdgcn_mfma_f32_32x32x16_bf16(Ah, blo[s], ahl, 0, 0, 0);
            alh = __builtin_amdgcn_mfma_f32_32x32x16_bf16(Al, bhi[s], alh, 0, 0, 0);
        }

        #pragma unroll
        for (int r = 0; r < 16; ++r) {
            int cl = ct * 32 + (r & 3) + 8 * (r >> 2) + 4 * kg;
            float dot = ahh[r] + ahl[r] + alh[r];
            float key = (dsq_s[cl] + 1024.0f) - 2.0f * dot;   // > 0 always
            unsigned long long v =
                ((unsigned long long)__float_as_uint(key) << 32) | (unsigned)cl;
            #pragma unroll
            for (int q = 0; q < 8; ++q) {
                bool lt = v < kk[q];
                unsigned long long mn = lt ? v : kk[q];
                unsigned long long mx = lt ? kk[q] : v;
                kk[q] = mn; v = mx;
            }
        }
    }

    uint4 wv;
    wv.x = (unsigned)(kk[0] & 0xFFFF) | ((unsigned)(kk[1] & 0xFFFF) << 16);
    wv.y = (unsigned)(kk[2] & 0xFFFF) | ((unsigned)(kk[3] & 0xFFFF) << 16);
    wv.z = (unsigned)(kk[4] & 0xFFFF) | ((unsigned)(kk[5] & 0xFFFF) << 16);
    wv.w = (unsigned)(kk[6] & 0xFFFF) | ((unsigned)(kk[7] & 0xFFFF) << 16);
    *reinterpret_cast<uint4*>(&cand_out[(size_t)row * 256 + kg * 4]) = wv;
}

// ---------- K2: exact refine v5 — dict streamed via LDS, NO reg prefetch ----
// Block = 64 rows x 16 cands = 1024 pairs, 256 threads (4 chains each).
// Per chunk: stage dictT_f32[16k][512cl] (32 KB coalesced, L2-resident) +
// x[64r][16k]; chains read LDS only. fmaf chain k=0..255 strictly sequential.
__global__ __launch_bounds__(256, 4) void refine_k(
    const float* __restrict__ x, const float* __restrict__ ws,
    float* __restrict__ out, unsigned* __restrict__ counts)
{
    __shared__ float dlds[16 * 516];   // [k_local][cluster], stride 516
    __shared__ float xlds[16 * 68];    // [k_local][row_local], stride 68
    __shared__ int   cidx[1024];
    __shared__ float distb[1024];

    const int t = threadIdx.x;
    const int rowBase = blockIdx.x * 64;
    const float* dictT = ws + WS_ROWLIST;   // fp32 [256][512]
    const unsigned short* candp = (const unsigned short*)(out + OUT_GEMB);

    // candidate ids: 64 rows x 16 slots
    #pragma unroll
    for (int i = 0; i < 4; ++i) {
        int q = t + i * 256;
        cidx[q] = (int)candp[(size_t)(rowBase + (q >> 4)) * 512 + (q & 15)];
    }
    __syncthreads();

    const int rl = t >> 2;          // row_local 0..63
    const int sb = (t & 3) * 4;     // slot base
    const int c0 = cidx[rl * 16 + sb + 0];
    const int c1 = cidx[rl * 16 + sb + 1];
    const int c2 = cidx[rl * 16 + sb + 2];
    const int c3 = cidx[rl * 16 + sb + 3];

    float a0 = 0.f, a1 = 0.f, a2 = 0.f, a3 = 0.f;

    for (int c = 0; c < 16; ++c) {
        __syncthreads();   // previous chunk fully consumed
        // stage dict chunk: 2048 float4s, 8 per thread, coalesced from L2
        #pragma unroll
        for (int i = 0; i < 8; ++i) {
            int g = t + i * 256;
            *reinterpret_cast<float4*>(&dlds[(g >> 7) * 516 + (g & 127) * 4]) =
                *reinterpret_cast<const float4*>(&dictT[(size_t)(c * 2048 + g) * 4]);
        }
        // stage x chunk
        {
            int f4 = t & 3, r = t >> 2;
            float4 xv = *reinterpret_cast<const float4*>(
                &x[(size_t)(rowBase + r) * D_DIM + c * 16 + f4 * 4]);
            xlds[(f4 * 4 + 0) * 68 + r] = xv.x;
            xlds[(f4 * 4 + 1) * 68 + r] = xv.y;
            xlds[(f4 * 4 + 2) * 68 + r] = xv.z;
            xlds[(f4 * 4 + 3) * 68 + r] = xv.w;
        }
        __syncthreads();
        // advance 4 chains by 16 k-steps (k = c*16 + kk, strictly sequential)
        #pragma unroll
        for (int kk = 0; kk < 16; ++kk) {
            float xv = xlds[kk * 68 + rl];
            const float* dr = &dlds[kk * 516];
            a0 = fmaf(xv, dr[c0], a0);
            a1 = fmaf(xv, dr[c1], a1);
            a2 = fmaf(xv, dr[c2], a2);
            a3 = fmaf(xv, dr[c3], a3);
        }
    }

    // epilogue: identical formula
    {
        float xs = ws[WS_XSQ + rowBase + rl];
        distb[rl * 16 + sb + 0] =
            __fsub_rn(__fadd_rn(xs, ws[WS_DSQ + c0]), __fmul_rn(2.0f, a0));
        distb[rl * 16 + sb + 1] =
            __fsub_rn(__fadd_rn(xs, ws[WS_DSQ + c1]), __fmul_rn(2.0f, a1));
        distb[rl * 16 + sb + 2] =
            __fsub_rn(__fadd_rn(xs, ws[WS_DSQ + c2]), __fmul_rn(2.0f, a2));
        distb[rl * 16 + sb + 3] =
            __fsub_rn(__fadd_rn(xs, ws[WS_DSQ + c3]), __fmul_rn(2.0f, a3));
    }
    __syncthreads();

    // exact lexicographic top-4 of the 16 candidates per row
    if (t < 64) {
        float bv0 = 3.4e38f, bv1 = 3.4e38f, bv2 = 3.4e38f, bv3 = 3.4e38f;
        int bi0 = 0x7FFFFFFF, bi1 = 0x7FFFFFFF, bi2 = 0x7FFFFFFF, bi3 = 0x7FFFFFFF;
        for (int s = 0; s < 16; ++s) {
            int p = t * 16 + s;
            float v = distb[p];
            int ci = cidx[p];
            if (v < bv3 || (v == bv3 && ci < bi3)) {
                if (v < bv2 || (v == bv2 && ci < bi2)) {
                    bv3 = bv2; bi3 = bi2;
                    if (v < bv1 || (v == bv1 && ci < bi1)) {
                        bv2 = bv1; bi2 = bi1;
                        if (v < bv0 || (v == bv0 && ci < bi0)) {
                            bv1 = bv0; bi1 = bi0;
                            bv0 = v; bi0 = ci;
                        } else { bv1 = v; bi1 = ci; }
                    } else { bv2 = v; bi2 = ci; }
                } else { bv3 = v; bi3 = ci; }
            }
        }
        int row = rowBase + t;
        out[OUT_TOPK + (size_t)row * 4 + 0] = (float)bi0;
        out[OUT_TOPK + (size_t)row * 4 + 1] = (float)bi1;
        out[OUT_TOPK + (size_t)row * 4 + 2] = (float)bi2;
        out[OUT_TOPK + (size_t)row * 4 + 3] = (float)bi3;
        atomicAdd(&counts[bi0], 1u);
        atomicAdd(&counts[bi1], 1u);
        atomicAdd(&counts[bi2], 1u);
        atomicAdd(&counts[bi3], 1u);
    }
}

// ---------- K2b: group_emb, fully coalesced (4 rows/block, 64 lanes/row) ----
__global__ __launch_bounds__(256, 4) void group_emb_k(
    const float* __restrict__ x, const float* __restrict__ dic,
    const float* __restrict__ topk, float* __restrict__ out)
{
    const int t = threadIdx.x;
    const int row = blockIdx.x * 4 + (t >> 6);
    const int k4 = (t & 63) * 4;
    int i0 = (int)topk[(size_t)row * 4 + 0];
    int i1 = (int)topk[(size_t)row * 4 + 1];
    int i2 = (int)topk[(size_t)row * 4 + 2];
    int i3 = (int)topk[(size_t)row * 4 + 3];
    float4 a = *reinterpret_cast<const float4*>(&dic[(size_t)i0 * D_DIM + k4]);
    float4 b = *reinterpret_cast<const float4*>(&dic[(size_t)i1 * D_DIM + k4]);
    float4 c = *reinterpret_cast<const float4*>(&dic[(size_t)i2 * D_DIM + k4]);
    float4 e = *reinterpret_cast<const float4*>(&dic[(size_t)i3 * D_DIM + k4]);
    float4 xv = *reinterpret_cast<const float4*>(&x[(size_t)row * D_DIM + k4]);
    float4 o;
    float g;
    g = __fmul_rn(__fadd_rn(__fadd_rn(__fadd_rn(a.x, b.x), c.x), e.x), 0.25f);
    o.x = __fadd_rn(__fsub_rn(g, xv.x), xv.x);
    g = __fmul_rn(__fadd_rn(__fadd_rn(__fadd_rn(a.y, b.y), c.y), e.y), 0.25f);
    o.y = __fadd_rn(__fsub_rn(g, xv.y), xv.y);
    g = __fmul_rn(__fadd_rn(__fadd_rn(__fadd_rn(a.z, b.z), c.z), e.z), 0.25f);
    o.z = __fadd_rn(__fsub_rn(g, xv.z), xv.z);
    g = __fmul_rn(__fadd_rn(__fadd_rn(__fadd_rn(a.w, b.w), c.w), e.w), 0.25f);
    o.w = __fadd_rn(__fsub_rn(g, xv.w), xv.w);
    *reinterpret_cast<float4*>(&out[OUT_GEMB + (size_t)row * D_DIM + k4]) = o;
}

// ---------- K3: exclusive prefix sum of counts ----------
__global__ void prefix_k(const unsigned* __restrict__ counts, unsigned* __restrict__ offsets) {
    __shared__ unsigned s[512];
    int t = threadIdx.x;
    unsigned my = counts[t];
    s[t] = my;
    __syncthreads();
    for (int off = 1; off < 512; off <<= 1) {
        unsigned v = (t >= off) ? s[t - off] : 0u;
        __syncthreads();
        s[t] += v;
        __syncthreads();
    }
    offsets[t] = s[t] - my;
    if (t == 511) offsets[512] = s[511];
}

// ---------- K4: scatter rows into cluster buckets (packed (c<<16)|row) ----------
__global__ void scatter_k(const float* __restrict__ topk, const unsigned* __restrict__ offsets,
                          unsigned* __restrict__ fill, unsigned* __restrict__ rowlist) {
    int row = blockIdx.x * 256 + threadIdx.x;
    #pragma unroll
    for (int k = 0; k < 4; ++k) {
        int c = (int)topk[row * 4 + k];
        unsigned p = atomicAdd(&fill[c], 1u);
        rowlist[offsets[c] + p] = ((unsigned)c << 16) | (unsigned)row;
    }
}

// ---------- K5: load-balanced segmented sum (encodings^T @ X) ----------
__global__ __launch_bounds__(256, 8) void cluster_sum2_k(
    const float* __restrict__ x, const unsigned* __restrict__ rowlist,
    float* __restrict__ isum)
{
    const int d = threadIdx.x;
    const int base = blockIdx.x * RPB;
    unsigned e0 = rowlist[base];
    int ccur = (int)(e0 >> 16);
    float acc = 0.f;
    #pragma unroll 4
    for (int j = 0; j < RPB; ++j) {
        unsigned e = rowlist[base + j];
        int c = (int)(e >> 16);
        float v = x[(e & 0xFFFFu) * D_DIM + d];
        if (c != ccur) {
            atomicAdd(&isum[ccur * D_DIM + d], acc);
            acc = 0.f;
            ccur = c;
        }
        acc += v;
    }
    atomicAdd(&isum[ccur * D_DIM + d], acc);
}

// ---------- K6: sequential decay scan + css EMA + laplace ----------
__global__ void ema_scalar_k(const float* __restrict__ css_in, const float* __restrict__ cnum_in,
                             const unsigned* __restrict__ counts,
                             float* __restrict__ ws, float* __restrict__ out) {
    __shared__ float sdecay[512];
    __shared__ float sred[512];
    __shared__ float scn[512];
    __shared__ unsigned smask[512];
    int t = threadIdx.x; // 512 threads
    unsigned cnt = counts[t];
    float size = (float)cnt;
    float mask = (cnt != 0u) ? 1.f : 0.f;
    float cnum_new = __fadd_rn(cnum_in[t], mask);
    scn[t] = cnum_new;
    smask[t] = cnt;
    __syncthreads();
    if (t == 0) {
        float d = 0.99f;
        for (int c = 0; c < 512; ++c) {
            if (smask[c] != 0u && scn[c] <= 10.0f)
                d = __fmul_rn(d, scn[c]) / 10.0f;   // (decay*c)/10, IEEE div
            sdecay[c] = d;
        }
    }
    __syncthreads();
    float d = sdecay[t];
    float css = css_in[t];
    float css_new = (cnt != 0u)
        ? __fadd_rn(__fmul_rn(css, d), __fmul_rn(size, __fsub_rn(1.f, d)))
        : css;
    out[OUT_CSS + t] = css_new;
    out[OUT_CNUM + t] = cnum_new;
    sred[t] = css_new;
    __syncthreads();
    for (int s = 256; s > 0; s >>= 1) {
        if (t < s) sred[t] += sred[t + s];
        __syncthreads();
    }
    float S = sred[0];
    float cs = __fmul_rn(__fdiv_rn(__fadd_rn(css_new, 1e-5f),
                                   __fadd_rn(S, 0.00512f)), S);
    ws[WS_CS + t] = cs;
    ws[WS_DCY + t] = d;
}

// ---------- K7: cluster_value EMA + dictionary normalize ----------
__global__ void final_k(const float* __restrict__ cv_in, const float* __restrict__ ws,
                        const unsigned* __restrict__ counts, float* __restrict__ out) {
    int c = blockIdx.x, d = threadIdx.x;
    float isum = ws[WS_ISUM + c * D_DIM + d];
    float dc = ws[WS_DCY + c];
    float cs = ws[WS_CS + c];
    unsigned cnt = counts[c];
    float cv = cv_in[c * D_DIM + d];
    float cvn = (cnt != 0u)
        ? __fadd_rn(__fmul_rn(cv, dc), __fmul_rn(isum, __fsub_rn(1.f, dc)))
        : cv;
    out[OUT_CV + c * D_DIM + d] = cvn;
    out[OUT_DICT + c * D_DIM + d] = (cnt != 0u) ? __fdiv_rn(cvn, cs) : cvn;
}

extern "C" void kernel_launch(void* const* d_in, const int* in_sizes, int n_in,
                              void* d_out, int out_size, void* d_ws, size_t ws_size,
                              hipStream_t stream) {
    const float* x       = (const float*)d_in[0];
    const float* dic     = (const float*)d_in[1];
    const float* css_in  = (const float*)d_in[2];
    const float* cv_in   = (const float*)d_in[3];
    const float* cnum_in = (const float*)d_in[4];
    float* out = (float*)d_out;
    float* ws  = (float*)d_ws;
    unsigned* counts  = (unsigned*)(ws + WS_COUNTS);
    unsigned* offsets = (unsigned*)(ws + WS_OFFSETS);
    unsigned* fill    = (unsigned*)(ws + WS_FILL);
    unsigned* rowlist = (unsigned*)(ws + WS_ROWLIST);

    zero_k<<<C_CLUST * D_DIM / 256, 256, 0, stream>>>(counts, fill, ws + WS_ISUM);
    prep_dict<<<C_CLUST, 256, 0, stream>>>(dic, ws);
    row_sq<<<N_ROWS, 256, 0, stream>>>(x, ws);

    stage1_cand<<<N_ROWS / 128, 256, 0, stream>>>(x, ws, out + OUT_GEMB);

    refine_k<<<N_ROWS / 64, 256, 0, stream>>>(x, ws, out, counts);
    group_emb_k<<<N_ROWS / 4, 256, 0, stream>>>(x, dic, out + OUT_TOPK, out + OUT_GEMB);

    prefix_k<<<1, 512, 0, stream>>>(counts, offsets);
    scatter_k<<<N_ROWS / 256, 256, 0, stream>>>(out + OUT_TOPK, offsets, fill, rowlist);
    cluster_sum2_k<<<N_ROWS * 4 / RPB, 256, 0, stream>>>(x, rowlist, ws + WS_ISUM);
    ema_scalar_k<<<1, 512, 0, stream>>>(css_in, cnum_in, counts, ws, out);
    final_k<<<C_CLUST, 256, 0, stream>>>(cv_in, ws, counts, out);
}